// Round 6
// baseline (192.107 us; speedup 1.0000x reference)
//
#include <hip/hip_runtime.h>

// Problem constants (from reference): B=4096, N_ELEM=2048, N_NODES=1024, E2=4096
#define B_SAMPLES 4096
#define N_ELEM    2048
#define N_NODES   1024
#define E2        4096
#define BLOCK     256                    // setup kernels
#define MBLOCK    256                    // main kernel block (finer granularity)
#define SLOTS     32                     // max entries/node (Poisson mean 4; P(>=32) ~ 1e-15)
#define S         2                      // samples per main block
#define MAIN_BLOCKS (B_SAMPLES / S)      // 2048

// Workspace layout (bytes):
//   [0, 4K)        : cnt[N_NODES]          (int)
//   [4K, 4K+512K)  : ell[SLOTS][N_NODES]   (float4 {wx, wy, bitcast(swz_eid), pad})
//   [4K+512K, +8K) : partial[MAIN_BLOCKS]  (float)
#define WS_CNT_OFF   0
#define WS_ELL_OFF   4096
#define WS_PART_OFF  (4096 + SLOTS * N_NODES * 16)

// LDS element swizzle: elem (4c+j) lives at j*512 + c. This makes phase-1's
// per-thread 4-consecutive-elem writes stride-1 across lanes (conflict-free)
// instead of 64B-per-lane (16-way conflict, the R2 disaster). The gather pays
// nothing: the build kernel stores the swizzled eid in the ELL table.
__host__ __device__ __forceinline__ int swz_eid(int eid) {
    return ((eid & 3) << 9) | (eid >> 2);
}

// ---------------------------------------------------------------------------
// Setup A: zero ELL table + counters. 128 blocks x 256 = one float4 each.
// ---------------------------------------------------------------------------
__global__ __launch_bounds__(BLOCK) void neq_zero_kernel(
    float4* __restrict__ ell, int* __restrict__ cnt)
{
    const int i = blockIdx.x * BLOCK + threadIdx.x;      // 0 .. 32767
    ell[i] = make_float4(0.f, 0.f, 0.f, 0.f);
    if (i < N_NODES) cnt[i] = 0;
}

// ---------------------------------------------------------------------------
// Setup B: build transposed-ELL via global atomics (order-independent sum).
// Stores the SWIZZLED eid (matches the LDS layout of the main kernel).
// ---------------------------------------------------------------------------
__global__ __launch_bounds__(BLOCK) void neq_build_kernel(
    const float* __restrict__ vecs, const int* __restrict__ node_ids,
    const int* __restrict__ elem_ids, int* __restrict__ cnt,
    float4* __restrict__ ell)
{
    const int j = blockIdx.x * BLOCK + threadIdx.x;      // 0 .. E2-1
    int nid = node_ids[j];
    int eid = swz_eid(elem_ids[j]);
    float2 v = ((const float2*)vecs)[j];
    int slot = atomicAdd(&cnt[nid], 1);                  // device-scope
    if (slot < SLOTS) {
        ell[slot * N_NODES + nid] = make_float4(v.x, v.y, __int_as_float(eid), 0.f);
    }
}

// Gather + accumulate one ELL entry into per-node accumulators.
// axial2[idx] = {axial_s0, axial_s1}; ACCX/ACCY are float2 over samples.
#define GFMA2(ACCX, ACCY, PK) do { \
    float2 gv = axial2[__float_as_int((PK).z)]; \
    (ACCX).x += gv.x * (PK).x; (ACCX).y += gv.y * (PK).x; \
    (ACCY).x += gv.x * (PK).y; (ACCY).y += gv.y * (PK).y; } while (0)

// ---------------------------------------------------------------------------
// Main: one block (256 threads) per S=2 samples. 2048 blocks = 8 blocks/CU
// (16 KiB LDS each) so neighbor blocks fill each other's phase gaps.
// Phase 1: 8 independent dwordx4 loads (16B/lane), in-register products,
// 8 stride-1 conflict-free ds_write_b64 into the swizzled axial2 layout.
// Phase 2: dynamic gather, 4 nodes/thread, ds_read_b64 per entry
// (ELL already carries swizzled eids; zero-padded rows contribute 0).
// ---------------------------------------------------------------------------
__global__ __launch_bounds__(MBLOCK, 8) void neq_main_kernel(
    const float* __restrict__ EA, const float* __restrict__ e,
    const float* __restrict__ q,  const float* __restrict__ r,
    const int* __restrict__ cnt, const float4* __restrict__ ell,
    float* __restrict__ partial)
{
    __shared__ float2 axial2[N_ELEM];    // 16 KiB, swizzled layout
    __shared__ float red[MBLOCK / 64];   // 4

    const int b0 = blockIdx.x * S;
    const int t = threadIdx.x;

    // ---- phase 1: 8 independent 16B loads ----
    const float4* EA4 = (const float4*)(EA + (size_t)b0 * N_ELEM);   // 512 f4/row
    const float4* e4  = (const float4*)(e  + (size_t)b0 * N_ELEM);
    float4 a00 = EA4[t];                 // row b0,   cols 4t..4t+3
    float4 a01 = EA4[t + 256];           // row b0,   cols 4(t+256)..
    float4 a10 = EA4[512 + t];           // row b0+1
    float4 a11 = EA4[512 + t + 256];
    float4 m00 = e4[t];
    float4 m01 = e4[t + 256];
    float4 m10 = e4[512 + t];
    float4 m11 = e4[512 + t + 256];

    // per-node counts (thread owns nodes t, t+256, t+512, t+768)
    int n0 = min(cnt[t], SLOTS);
    int n1 = min(cnt[t + 256], SLOTS);
    int n2 = min(cnt[t + 512], SLOTS);
    int n3 = min(cnt[t + 768], SLOTS);
    int kmax = max(max(n0, n1), max(n2, n3));

    // products + swizzled writes: group c = t (retires a*0/m*0 early)
    {
        float4 p0, p1;
        p0.x = a00.x * m00.x; p0.y = a00.y * m00.y; p0.z = a00.z * m00.z; p0.w = a00.w * m00.w;
        p1.x = a10.x * m10.x; p1.y = a10.y * m10.y; p1.z = a10.z * m10.z; p1.w = a10.w * m10.w;
        axial2[t]        = make_float2(p0.x, p1.x);      // elem 4t+0
        axial2[t + 512]  = make_float2(p0.y, p1.y);      // elem 4t+1
        axial2[t + 1024] = make_float2(p0.z, p1.z);      // elem 4t+2
        axial2[t + 1536] = make_float2(p0.w, p1.w);      // elem 4t+3
    }
    // group c = t+256
    {
        float4 p0, p1;
        p0.x = a01.x * m01.x; p0.y = a01.y * m01.y; p0.z = a01.z * m01.z; p0.w = a01.w * m01.w;
        p1.x = a11.x * m11.x; p1.y = a11.y * m11.y; p1.z = a11.z * m11.z; p1.w = a11.w * m11.w;
        axial2[t + 256]  = make_float2(p0.x, p1.x);
        axial2[t + 768]  = make_float2(p0.y, p1.y);
        axial2[t + 1280] = make_float2(p0.z, p1.z);
        axial2[t + 1792] = make_float2(p0.w, p1.w);
    }
    __syncthreads();

    // ---- phase 2: gather, 4 nodes per thread ----
    float2 accx0 = make_float2(0.f, 0.f), accy0 = make_float2(0.f, 0.f);
    float2 accx1 = make_float2(0.f, 0.f), accy1 = make_float2(0.f, 0.f);
    float2 accx2 = make_float2(0.f, 0.f), accy2 = make_float2(0.f, 0.f);
    float2 accx3 = make_float2(0.f, 0.f), accy3 = make_float2(0.f, 0.f);

    for (int k = 0; k < kmax; ++k) {
        const float4* row = ell + (size_t)k * N_NODES;
        float4 pk0 = row[t];                             // coalesced 1KB/wave
        float4 pk1 = row[t + 256];
        float4 pk2 = row[t + 512];
        float4 pk3 = row[t + 768];
        GFMA2(accx0, accy0, pk0);
        GFMA2(accx1, accy1, pk1);
        GFMA2(accx2, accy2, pk2);
        GFMA2(accx3, accy3, pk3);
    }

    // ---- phase 3: residual & sum of squares (per sample to limit pressure) ----
    float acc = 0.f;
#pragma unroll
    for (int s = 0; s < S; ++s) {
        const float2* q2 = (const float2*)(q + (size_t)(b0 + s) * N_NODES * 2);
        const float2* r2 = (const float2*)(r + (size_t)(b0 + s) * N_NODES * 2);
        float2 qa = q2[t],       ra = r2[t];
        float2 qb = q2[t + 256], rb = r2[t + 256];
        float2 qc = q2[t + 512], rc = r2[t + 512];
        float2 qd = q2[t + 768], rd = r2[t + 768];
        float ax, ay, x, y;
        ax = (s == 0) ? accx0.x : accx0.y;  ay = (s == 0) ? accy0.x : accy0.y;
        x = ax - qa.x - ra.x;  y = ay - qa.y - ra.y;  acc += x * x + y * y;
        ax = (s == 0) ? accx1.x : accx1.y;  ay = (s == 0) ? accy1.x : accy1.y;
        x = ax - qb.x - rb.x;  y = ay - qb.y - rb.y;  acc += x * x + y * y;
        ax = (s == 0) ? accx2.x : accx2.y;  ay = (s == 0) ? accy2.x : accy2.y;
        x = ax - qc.x - rc.x;  y = ay - qc.y - rc.y;  acc += x * x + y * y;
        ax = (s == 0) ? accx3.x : accx3.y;  ay = (s == 0) ? accy3.x : accy3.y;
        x = ax - qd.x - rd.x;  y = ay - qd.y - rd.y;  acc += x * x + y * y;
    }

    // ---- wave + block reduce (4 waves) ----
#pragma unroll
    for (int off = 32; off > 0; off >>= 1)
        acc += __shfl_down(acc, off, 64);
    if ((t & 63) == 0) red[t >> 6] = acc;
    __syncthreads();
    if (t == 0) partial[blockIdx.x] = red[0] + red[1] + red[2] + red[3];
}

// Reduce the per-block partials and apply the mean scale.
__global__ __launch_bounds__(1024) void neq_reduce_kernel(
    const float* __restrict__ partial, float* __restrict__ out)
{
    __shared__ float red[1024 / 64];
    const int t = threadIdx.x;
    float acc = partial[t] + partial[t + 1024];          // MAIN_BLOCKS == 2048
#pragma unroll
    for (int off = 32; off > 0; off >>= 1)
        acc += __shfl_down(acc, off, 64);
    if ((t & 63) == 0) red[t >> 6] = acc;
    __syncthreads();
    if (t == 0) {
        float s = 0.f;
#pragma unroll
        for (int w = 0; w < 1024 / 64; ++w) s += red[w];
        const float inv_n = 1.0f / (float)((size_t)B_SAMPLES * N_NODES * 2);
        out[0] = s * inv_n;
    }
}

extern "C" void kernel_launch(void* const* d_in, const int* in_sizes, int n_in,
                              void* d_out, int out_size, void* d_ws, size_t ws_size,
                              hipStream_t stream) {
    const float* EA       = (const float*)d_in[0];
    const float* e        = (const float*)d_in[1];
    const float* q        = (const float*)d_in[2];
    const float* r        = (const float*)d_in[3];
    const float* vecs     = (const float*)d_in[4];
    const int*   node_ids = (const int*)d_in[5];
    const int*   elem_ids = (const int*)d_in[6];

    char* ws = (char*)d_ws;
    int*    cnt     = (int*)(ws + WS_CNT_OFF);
    float4* ell     = (float4*)(ws + WS_ELL_OFF);
    float*  partial = (float*)(ws + WS_PART_OFF);

    neq_zero_kernel<<<(SLOTS * N_NODES) / BLOCK, BLOCK, 0, stream>>>(ell, cnt);
    neq_build_kernel<<<E2 / BLOCK, BLOCK, 0, stream>>>(
        vecs, node_ids, elem_ids, cnt, ell);
    neq_main_kernel<<<MAIN_BLOCKS, MBLOCK, 0, stream>>>(
        EA, e, q, r, cnt, ell, partial);
    neq_reduce_kernel<<<1, 1024, 0, stream>>>(partial, (float*)d_out);
}

// Round 7
// 163.255 us; speedup vs baseline: 1.1767x; 1.1767x over previous
//
#include <hip/hip_runtime.h>

// Problem constants (from reference): B=4096, N_ELEM=2048, N_NODES=1024, E2=4096
#define B_SAMPLES 4096
#define N_ELEM    2048
#define N_NODES   1024
#define E2        4096
#define BLOCK     256                    // setup kernels
#define MBLOCK    512                    // main kernel block
#define SLOTS     32                     // max entries/node (Poisson mean 4; P(>=32) ~ 1e-15)
#define S         8                      // samples per main block
#define MAIN_BLOCKS (B_SAMPLES / S)      // 512

// Workspace layout (bytes):
//   [0, 4K)          : cnt[N_NODES]            (int)
//   [4K, +256K)      : ellw[SLOTS][N_NODES]    (float2 {wx, wy})
//   [4K+256K, +128K) : ellid[SLOTS][N_NODES]   (int swizzled eid)
//   [4K+384K, +2K)   : partial[MAIN_BLOCKS]    (float)
#define WS_CNT_OFF    0
#define WS_ELLW_OFF   4096
#define WS_ELLID_OFF  (4096 + SLOTS * N_NODES * 8)
#define WS_PART_OFF   (WS_ELLID_OFF + SLOTS * N_NODES * 4)

// LDS element swizzle: elem (4c+j) lives at slot j*512 + c, so phase-1's
// per-thread writes of 4 consecutive elems become 4 stride-1 (16B/lane)
// conflict-free b128 stores. Gather pays nothing: build stores swizzled ids.
__host__ __device__ __forceinline__ int swz_eid(int eid) {
    return ((eid & 3) << 9) | (eid >> 2);
}

// ---------------------------------------------------------------------------
// Setup A: zero ELL weight/id tables + counters. 128 blocks x 256.
// ---------------------------------------------------------------------------
__global__ __launch_bounds__(BLOCK) void neq_zero_kernel(
    float2* __restrict__ ellw, int* __restrict__ ellid, int* __restrict__ cnt)
{
    const int i = blockIdx.x * BLOCK + threadIdx.x;      // 0 .. 32767
    ellw[i] = make_float2(0.f, 0.f);
    ellid[i] = 0;
    if (i < N_NODES) cnt[i] = 0;
}

// ---------------------------------------------------------------------------
// Setup B: build transposed-ELL via global atomics (order-independent sum).
// Stores weights (float2) and SWIZZLED eid (int) in separate arrays: 12B/entry
// instead of 16B -> 25% less gather traffic in the main kernel.
// ---------------------------------------------------------------------------
__global__ __launch_bounds__(BLOCK) void neq_build_kernel(
    const float* __restrict__ vecs, const int* __restrict__ node_ids,
    const int* __restrict__ elem_ids, int* __restrict__ cnt,
    float2* __restrict__ ellw, int* __restrict__ ellid)
{
    const int j = blockIdx.x * BLOCK + threadIdx.x;      // 0 .. E2-1
    int nid = node_ids[j];
    int sid = swz_eid(elem_ids[j]);
    float2 v = ((const float2*)vecs)[j];
    int slot = atomicAdd(&cnt[nid], 1);                  // device-scope
    if (slot < SLOTS) {
        ellw[slot * N_NODES + nid] = v;
        ellid[slot * N_NODES + nid] = sid;
    }
}

// FMA of a float4 (4 samples) by a scalar weight into a float4 accumulator.
#define FMA4(A, V, W) do { (A).x += (V).x * (W); (A).y += (V).y * (W); \
                           (A).z += (V).z * (W); (A).w += (V).w * (W); } while (0)

// ---------------------------------------------------------------------------
// Main: one block (512 threads) per S=8 samples; 512 blocks = 2 blocks/CU
// (64 KiB LDS each). S=8 halves the per-sample-amortized ELL re-read traffic
// vs S=4 (R5): total CU intake drops 328 -> ~203 MB, which is the binding
// resource (R5 ran at ~12.5 B/cyc/CU ~= the m13 per-CU streaming rate; all
// latency/MLP attacks were null).
// Phase 1: 16 independent dwordx4 loads, in-register transpose, 16 stride-1
// conflict-free b128 LDS writes into swizzled split tables (A: samples 0-3,
// B: samples 4-7). Phase 2: dynamic gather, 2 nodes/thread, 12B/entry.
// Zero-padded slots contribute exactly 0 (w=0, id=0 -> valid LDS slot).
// ---------------------------------------------------------------------------
__global__ __launch_bounds__(MBLOCK, 4) void neq_main_kernel(
    const float* __restrict__ EA, const float* __restrict__ e,
    const float* __restrict__ q,  const float* __restrict__ r,
    const int* __restrict__ cnt, const float2* __restrict__ ellw,
    const int* __restrict__ ellid, float* __restrict__ partial)
{
    __shared__ float4 axialA[N_ELEM];    // 32 KiB: samples 0-3, swizzled
    __shared__ float4 axialB[N_ELEM];    // 32 KiB: samples 4-7, swizzled
    __shared__ float red[MBLOCK / 64];   // 8

    const int b0 = blockIdx.x * S;
    const int t = threadIdx.x;

    // ---- phase 1: 16 independent 16B loads (8 KB/wave in flight) ----
    const float4* EA4 = (const float4*)(EA + (size_t)b0 * N_ELEM);   // 512 f4/row
    const float4* e4  = (const float4*)(e  + (size_t)b0 * N_ELEM);
    float4 ea0 = EA4[0 * 512 + t];
    float4 ea1 = EA4[1 * 512 + t];
    float4 ea2 = EA4[2 * 512 + t];
    float4 ea3 = EA4[3 * 512 + t];
    float4 me0 = e4 [0 * 512 + t];
    float4 me1 = e4 [1 * 512 + t];
    float4 me2 = e4 [2 * 512 + t];
    float4 me3 = e4 [3 * 512 + t];

    // per-node counts (thread owns nodes t, t+512)
    int c0n = min(cnt[t], SLOTS);
    int c1n = min(cnt[t + 512], SLOTS);
    int kmax = max(c0n, c1n);

    // section A: samples 0-3 -> products + transpose + conflict-free writes
    {
        float4 p0, p1, p2, p3;           // p_s = product of sample s, elems 4t..4t+3
        p0.x = ea0.x * me0.x; p0.y = ea0.y * me0.y; p0.z = ea0.z * me0.z; p0.w = ea0.w * me0.w;
        p1.x = ea1.x * me1.x; p1.y = ea1.y * me1.y; p1.z = ea1.z * me1.z; p1.w = ea1.w * me1.w;
        p2.x = ea2.x * me2.x; p2.y = ea2.y * me2.y; p2.z = ea2.z * me2.z; p2.w = ea2.w * me2.w;
        p3.x = ea3.x * me3.x; p3.y = ea3.y * me3.y; p3.z = ea3.z * me3.z; p3.w = ea3.w * me3.w;
        axialA[t]        = make_float4(p0.x, p1.x, p2.x, p3.x);   // elem 4t+0
        axialA[512 + t]  = make_float4(p0.y, p1.y, p2.y, p3.y);   // elem 4t+1
        axialA[1024 + t] = make_float4(p0.z, p1.z, p2.z, p3.z);   // elem 4t+2
        axialA[1536 + t] = make_float4(p0.w, p1.w, p2.w, p3.w);   // elem 4t+3
    }
    // section B: samples 4-7
    {
        float4 fa0 = EA4[4 * 512 + t];
        float4 fa1 = EA4[5 * 512 + t];
        float4 fa2 = EA4[6 * 512 + t];
        float4 fa3 = EA4[7 * 512 + t];
        float4 fm0 = e4 [4 * 512 + t];
        float4 fm1 = e4 [5 * 512 + t];
        float4 fm2 = e4 [6 * 512 + t];
        float4 fm3 = e4 [7 * 512 + t];
        float4 p0, p1, p2, p3;
        p0.x = fa0.x * fm0.x; p0.y = fa0.y * fm0.y; p0.z = fa0.z * fm0.z; p0.w = fa0.w * fm0.w;
        p1.x = fa1.x * fm1.x; p1.y = fa1.y * fm1.y; p1.z = fa1.z * fm1.z; p1.w = fa1.w * fm1.w;
        p2.x = fa2.x * fm2.x; p2.y = fa2.y * fm2.y; p2.z = fa2.z * fm2.z; p2.w = fa2.w * fm2.w;
        p3.x = fa3.x * fm3.x; p3.y = fa3.y * fm3.y; p3.z = fa3.z * fm3.z; p3.w = fa3.w * fm3.w;
        axialB[t]        = make_float4(p0.x, p1.x, p2.x, p3.x);
        axialB[512 + t]  = make_float4(p0.y, p1.y, p2.y, p3.y);
        axialB[1024 + t] = make_float4(p0.z, p1.z, p2.z, p3.z);
        axialB[1536 + t] = make_float4(p0.w, p1.w, p2.w, p3.w);
    }
    __syncthreads();

    // ---- phase 2: gather, 2 nodes per thread, 12B/entry ----
    float4 xA0 = make_float4(0.f, 0.f, 0.f, 0.f);   // node t,    x, samples 0-3
    float4 yA0 = make_float4(0.f, 0.f, 0.f, 0.f);   // node t,    y, samples 0-3
    float4 xB0 = make_float4(0.f, 0.f, 0.f, 0.f);   // node t,    x, samples 4-7
    float4 yB0 = make_float4(0.f, 0.f, 0.f, 0.f);
    float4 xA1 = make_float4(0.f, 0.f, 0.f, 0.f);   // node t+512
    float4 yA1 = make_float4(0.f, 0.f, 0.f, 0.f);
    float4 xB1 = make_float4(0.f, 0.f, 0.f, 0.f);
    float4 yB1 = make_float4(0.f, 0.f, 0.f, 0.f);

    for (int k = 0; k < kmax; ++k) {
        const float2* rw  = ellw  + (size_t)k * N_NODES;
        const int*    rid = ellid + (size_t)k * N_NODES;
        float2 w0 = rw[t];
        float2 w1 = rw[t + 512];
        int i0 = rid[t];
        int i1 = rid[t + 512];
        float4 A0 = axialA[i0];
        float4 B0 = axialB[i0];
        float4 A1 = axialA[i1];
        float4 B1 = axialB[i1];
        FMA4(xA0, A0, w0.x);  FMA4(yA0, A0, w0.y);
        FMA4(xB0, B0, w0.x);  FMA4(yB0, B0, w0.y);
        FMA4(xA1, A1, w1.x);  FMA4(yA1, A1, w1.y);
        FMA4(xB1, B1, w1.x);  FMA4(yB1, B1, w1.y);
    }

    // ---- phase 3: residual & sum of squares (per sample; q/r loaded late) ----
    float acc = 0.f;
#pragma unroll
    for (int s = 0; s < 4; ++s) {                        // samples 0-3 (A set)
        const float2* q2 = (const float2*)(q + (size_t)(b0 + s) * N_NODES * 2);
        const float2* r2 = (const float2*)(r + (size_t)(b0 + s) * N_NODES * 2);
        float2 qa = q2[t],       ra = r2[t];
        float2 qb = q2[t + 512], rb = r2[t + 512];
        float ax0 = (s == 0) ? xA0.x : (s == 1) ? xA0.y : (s == 2) ? xA0.z : xA0.w;
        float ay0 = (s == 0) ? yA0.x : (s == 1) ? yA0.y : (s == 2) ? yA0.z : yA0.w;
        float ax1 = (s == 0) ? xA1.x : (s == 1) ? xA1.y : (s == 2) ? xA1.z : xA1.w;
        float ay1 = (s == 0) ? yA1.x : (s == 1) ? yA1.y : (s == 2) ? yA1.z : yA1.w;
        float x = ax0 - qa.x - ra.x;
        float y = ay0 - qa.y - ra.y;
        acc += x * x + y * y;
        x = ax1 - qb.x - rb.x;
        y = ay1 - qb.y - rb.y;
        acc += x * x + y * y;
    }
#pragma unroll
    for (int s = 0; s < 4; ++s) {                        // samples 4-7 (B set)
        const float2* q2 = (const float2*)(q + (size_t)(b0 + 4 + s) * N_NODES * 2);
        const float2* r2 = (const float2*)(r + (size_t)(b0 + 4 + s) * N_NODES * 2);
        float2 qa = q2[t],       ra = r2[t];
        float2 qb = q2[t + 512], rb = r2[t + 512];
        float ax0 = (s == 0) ? xB0.x : (s == 1) ? xB0.y : (s == 2) ? xB0.z : xB0.w;
        float ay0 = (s == 0) ? yB0.x : (s == 1) ? yB0.y : (s == 2) ? yB0.z : yB0.w;
        float ax1 = (s == 0) ? xB1.x : (s == 1) ? xB1.y : (s == 2) ? xB1.z : xB1.w;
        float ay1 = (s == 0) ? yB1.x : (s == 1) ? yB1.y : (s == 2) ? yB1.z : yB1.w;
        float x = ax0 - qa.x - ra.x;
        float y = ay0 - qa.y - ra.y;
        acc += x * x + y * y;
        x = ax1 - qb.x - rb.x;
        y = ay1 - qb.y - rb.y;
        acc += x * x + y * y;
    }

    // ---- wave + block reduce (8 waves) ----
#pragma unroll
    for (int off = 32; off > 0; off >>= 1)
        acc += __shfl_down(acc, off, 64);
    if ((t & 63) == 0) red[t >> 6] = acc;
    __syncthreads();
    if (t == 0) {
        float s = 0.f;
#pragma unroll
        for (int w = 0; w < MBLOCK / 64; ++w) s += red[w];
        partial[blockIdx.x] = s;
    }
}

// Reduce the per-block partials and apply the mean scale.
__global__ __launch_bounds__(512) void neq_reduce_kernel(
    const float* __restrict__ partial, float* __restrict__ out)
{
    __shared__ float red[512 / 64];
    const int t = threadIdx.x;
    float acc = partial[t];                              // MAIN_BLOCKS == 512
#pragma unroll
    for (int off = 32; off > 0; off >>= 1)
        acc += __shfl_down(acc, off, 64);
    if ((t & 63) == 0) red[t >> 6] = acc;
    __syncthreads();
    if (t == 0) {
        float s = 0.f;
#pragma unroll
        for (int w = 0; w < 512 / 64; ++w) s += red[w];
        const float inv_n = 1.0f / (float)((size_t)B_SAMPLES * N_NODES * 2);
        out[0] = s * inv_n;
    }
}

extern "C" void kernel_launch(void* const* d_in, const int* in_sizes, int n_in,
                              void* d_out, int out_size, void* d_ws, size_t ws_size,
                              hipStream_t stream) {
    const float* EA       = (const float*)d_in[0];
    const float* e        = (const float*)d_in[1];
    const float* q        = (const float*)d_in[2];
    const float* r        = (const float*)d_in[3];
    const float* vecs     = (const float*)d_in[4];
    const int*   node_ids = (const int*)d_in[5];
    const int*   elem_ids = (const int*)d_in[6];

    char* ws = (char*)d_ws;
    int*    cnt     = (int*)(ws + WS_CNT_OFF);
    float2* ellw    = (float2*)(ws + WS_ELLW_OFF);
    int*    ellid   = (int*)(ws + WS_ELLID_OFF);
    float*  partial = (float*)(ws + WS_PART_OFF);

    neq_zero_kernel<<<(SLOTS * N_NODES) / BLOCK, BLOCK, 0, stream>>>(ellw, ellid, cnt);
    neq_build_kernel<<<E2 / BLOCK, BLOCK, 0, stream>>>(
        vecs, node_ids, elem_ids, cnt, ellw, ellid);
    neq_main_kernel<<<MAIN_BLOCKS, MBLOCK, 0, stream>>>(
        EA, e, q, r, cnt, ellw, ellid, partial);
    neq_reduce_kernel<<<1, 512, 0, stream>>>(partial, (float*)d_out);
}